// Round 6
// baseline (125.569 us; speedup 1.0000x reference)
//
#include <hip/hip_runtime.h>
#include <hip/hip_bf16.h>

#define BB 4
#define IN_DIM 8
#define OUT_DIM 64
#define N_WIN 64
#define N_SEQ 4096
#define N_REAL 6144

#define OG 4                       // output channels per block
#define TTILE 128                  // t per block: 2 per lane (t0+tid, t0+64+tid)
#define ZROWS (TTILE + N_WIN - 1)  // 191 rows incl. halo
#define ZPITCH 192                 // plane pitch; bank = row mod 32, lane-stride 1 -> free

__global__ __launch_bounds__(64)
void astrf_fused(const float* __restrict__ x,
                 const float* __restrict__ w,
                 const float* __restrict__ bias,
                 const int* __restrict__ sidx,
                 float* __restrict__ out)
{
    __shared__ float zsh[IN_DIM * ZPITCH];        // 6 KB  [i][row]
    __shared__ float wsh[N_WIN * IN_DIM * OG];    // 8 KB  [(i*64+l)][o]

    const int tid = threadIdx.x;
    const int t0  = blockIdx.x * TTILE;
    const int o0  = blockIdx.y * OG;
    const int b   = blockIdx.z;

    // ---- zero timeline: b32 stride-1 (conflict-free) ----
    #pragma unroll
    for (int m = 0; m < IN_DIM * ZPITCH / 64; ++m) zsh[m * 64 + tid] = 0.f;

    // ---- stage weights: LDS addr = tid + 64m (consecutive, conflict-free);
    //      global reads = 4 segments of 16 consecutive floats (full 64B lines) ----
    {
        const int o   = tid & 3;
        const int rb  = tid >> 2;               // 0..15
        const float* wg = w + (size_t)(o0 + o) * (IN_DIM * N_WIN);
        #pragma unroll
        for (int m = 0; m < (OG * IN_DIM * N_WIN) / 64; ++m) {   // 32 iters
            int rem = rb + 16 * m;              // i*64+l
            wsh[rem * OG + o] = wg[rem];
        }
    }
    __syncthreads();

    // ---- scatter: coalesced scan of all sources (no dependent binary search) ----
    const int* idxb = sidx + b * N_SEQ;
    const int vlo = t0 - (N_WIN - 1);
    for (int k = tid; k < N_SEQ; k += 64) {
        int r = idxb[k] - vlo;
        if ((unsigned)r < (unsigned)ZROWS) {
            const float* xp = x + (size_t)b * IN_DIM * N_SEQ + k;
            #pragma unroll
            for (int i = 0; i < IN_DIM; ++i)
                zsh[i * ZPITCH + r] = xp[(size_t)i * N_SEQ];
        }
    }
    __syncthreads();

    // ---- dense correlation: lane owns t = t0+tid and t0+64+tid ----
    float acc[OG][2];
    #pragma unroll
    for (int o = 0; o < OG; ++o) acc[o][0] = acc[o][1] = 0.f;

    const int rb0 = tid + (N_WIN - 1);          // row for t0+tid,    l=0
    const int rb1 = tid + (N_WIN - 1) + 64;     // row for t0+64+tid, l=0

    for (int i = 0; i < IN_DIM; ++i) {
        const float* zp = &zsh[i * ZPITCH];
        const float* wp = &wsh[(i * N_WIN) * OG];
        #pragma unroll 4
        for (int l = 0; l < N_WIN; ++l) {
            const float z0 = zp[rb0 - l];                       // b32, lane-stride 1
            const float z1 = zp[rb1 - l];
            const float4 wv = *(const float4*)&wp[l * OG];      // uniform broadcast
            acc[0][0] += wv.x * z0;  acc[0][1] += wv.x * z1;
            acc[1][0] += wv.y * z0;  acc[1][1] += wv.y * z1;
            acc[2][0] += wv.z * z0;  acc[2][1] += wv.z * z1;
            acc[3][0] += wv.w * z0;  acc[3][1] += wv.w * z1;
        }
    }

    // ---- epilogue: bias + coalesced b32 stores ----
    #pragma unroll
    for (int o = 0; o < OG; ++o) {
        const float bv = bias[o0 + o];
        float* op = out + ((size_t)b * OUT_DIM + o0 + o) * N_REAL + t0 + tid;
        op[0]  = acc[o][0] + bv;
        op[64] = acc[o][1] + bv;
    }
}

extern "C" void kernel_launch(void* const* d_in, const int* in_sizes, int n_in,
                              void* d_out, int out_size, void* d_ws, size_t ws_size,
                              hipStream_t stream) {
    const float* px = nullptr; const float* pw = nullptr;
    const float* pb = nullptr; const int* ps = nullptr;

    for (int i = 0; i < n_in; ++i) {
        switch (in_sizes[i]) {
            case BB * IN_DIM * N_SEQ:        px = (const float*)d_in[i]; break; // 131072 x
            case OUT_DIM * IN_DIM * N_WIN:   pw = (const float*)d_in[i]; break; // 32768 weight
            case OUT_DIM:                    pb = (const float*)d_in[i]; break; // 64 bias
            case BB * N_SEQ:                 ps = (const int*)d_in[i];   break; // 16384 idx
            default: break;                                                      // nRealLen scalar
        }
    }
    if (!px || !pw || !pb || !ps) {
        px = (const float*)d_in[0]; pw = (const float*)d_in[1];
        pb = (const float*)d_in[2]; ps = (const int*)d_in[3];
    }

    float* out = (float*)d_out;
    dim3 grid(N_REAL / TTILE, OUT_DIM / OG, BB);  // 48 x 16 x 4 = 3072 blocks (1 wave each)
    astrf_fused<<<grid, dim3(64), 0, stream>>>(px, pw, pb, ps, out);
}

// Round 7
// 74.475 us; speedup vs baseline: 1.6861x; 1.6861x over previous
//
#include <hip/hip_runtime.h>
#include <hip/hip_bf16.h>

#define BB 4
#define IN_DIM 8
#define OUT_DIM 64
#define N_WIN 64
#define N_SEQ 4096
#define N_REAL 6144

#define ZR 6208   // timeline rows per batch: 63 zero-pad + 6144 + 1 spare

typedef __attribute__((ext_vector_type(8)))  short short8;
typedef __attribute__((ext_vector_type(16))) float floatx16;

static __device__ __forceinline__ unsigned short f2bf(float f) {
    union { float f; unsigned int u; } v; v.f = f;
    unsigned int r = v.u + 0x7fffu + ((v.u >> 16) & 1u);   // round-nearest-even
    return (unsigned short)(r >> 16);
}

// ---- K0: zero the scatter timeline (d_ws is poisoned 0xAA each call) ----
__global__ __launch_bounds__(256) void k_zero(uint4* p, int n) {
    int i = blockIdx.x * 256 + threadIdx.x;
    if (i < n) p[i] = make_uint4(0u, 0u, 0u, 0u);
}

// ---- K1: scatter x -> bf16 timeline zf[b][tau+63][i]; transpose w -> w2[l][o][i] ----
__global__ __launch_bounds__(256)
void k_prep(const float* __restrict__ x, const float* __restrict__ w,
            const int* __restrict__ sidx,
            unsigned short* __restrict__ w2, unsigned short* __restrict__ zf)
{
    const int bid = blockIdx.x, tid = threadIdx.x;
    if (bid < 64) {                       // scatter: one thread per (b,s)
        int tg = bid * 256 + tid;         // 0..16383
        int b = tg >> 12, s = tg & 4095;
        int tau = sidx[b * N_SEQ + s];    // unique per b -> race-free
        const float* xp = x + (size_t)b * IN_DIM * N_SEQ + s;
        unsigned short v[8];
        #pragma unroll
        for (int i = 0; i < 8; ++i) v[i] = f2bf(xp[(size_t)i * N_SEQ]);
        uint4 pk;
        pk.x = v[0] | (v[1] << 16); pk.y = v[2] | (v[3] << 16);
        pk.z = v[4] | (v[5] << 16); pk.w = v[6] | (v[7] << 16);
        *(uint4*)(zf + ((size_t)b * ZR + tau + 63) * 8) = pk;
    } else {                              // w transpose: one thread per (o,l)
        int tg = (bid - 64) * 256 + tid;  // 0..4095
        int l = tg & 63, o = tg >> 6;
        const float* wp = w + (size_t)o * IN_DIM * N_WIN + l;
        unsigned short v[8];
        #pragma unroll
        for (int i = 0; i < 8; ++i) v[i] = f2bf(wp[(size_t)i * N_WIN]);
        uint4 pk;
        pk.x = v[0] | (v[1] << 16); pk.y = v[2] | (v[3] << 16);
        pk.z = v[4] | (v[5] << 16); pk.w = v[6] | (v[7] << 16);
        *(uint4*)(w2 + ((size_t)l * OUT_DIM + o) * 8) = pk;
    }
}

// ---- K2: MFMA GEMM. Block = 32 t x 64 o, 2 waves (one 32-o half each). ----
__global__ __launch_bounds__(128)
void k_gemm(const unsigned short* __restrict__ w2,
            const unsigned short* __restrict__ zf,
            const float* __restrict__ bias, float* __restrict__ out)
{
    __shared__ unsigned short zlds[96 * 8];   // 96 timeline rows x 8 bf16 = 1.5 KB

    const int tid = threadIdx.x;
    const int t0  = blockIdx.x * 32;
    const int b   = blockIdx.y;

    // stage rows tau = t0-63 .. t0+32 (global rows t0..t0+95): coalesced 16B/lane
    if (tid < 96)
        *(uint4*)(zlds + tid * 8) =
            *(const uint4*)(zf + ((size_t)b * ZR + t0 + tid) * 8);
    __syncthreads();

    const int mh = tid >> 6;          // wave id: which 32-o half
    const int ln = tid & 31;          // n (t) / m lane coordinate
    const int lq = (tid >> 5) & 1;    // k-half within wave

    floatx16 acc = {};
    const short8* wv = (const short8*)w2;
    const short8* zv = (const short8*)zlds;

    #pragma unroll 8
    for (int ks = 0; ks < 32; ++ks) {
        const int l = 2 * ks + lq;                       // lag for this k-half
        short8 a = wv[l * OUT_DIM + mh * 32 + ln];       // A[m=o][k=(l,i)]  (L2-hot)
        short8 bz = zv[ln + 63 - l];                     // B[k=(l,i)][n=t]  (LDS b128)
        acc = __builtin_amdgcn_mfma_f32_32x32x16_bf16(a, bz, acc, 0, 0, 0);
    }

    // C/D layout (m74/m101): col=lane&31 -> t, row=(p&3)+8*(p>>2)+4*(lane>>5) -> o
    #pragma unroll
    for (int p = 0; p < 16; ++p) {
        int o = (p & 3) + 8 * (p >> 2) + 4 * lq + mh * 32;
        out[((size_t)b * OUT_DIM + o) * N_REAL + t0 + ln] = acc[p] + bias[o];
    }
}

extern "C" void kernel_launch(void* const* d_in, const int* in_sizes, int n_in,
                              void* d_out, int out_size, void* d_ws, size_t ws_size,
                              hipStream_t stream) {
    const float* px = nullptr; const float* pw = nullptr;
    const float* pb = nullptr; const int* ps = nullptr;

    for (int i = 0; i < n_in; ++i) {
        switch (in_sizes[i]) {
            case BB * IN_DIM * N_SEQ:        px = (const float*)d_in[i]; break; // x
            case OUT_DIM * IN_DIM * N_WIN:   pw = (const float*)d_in[i]; break; // weight
            case OUT_DIM:                    pb = (const float*)d_in[i]; break; // bias
            case BB * N_SEQ:                 ps = (const int*)d_in[i];   break; // sourceIdx
            default: break;
        }
    }
    if (!px || !pw || !pb || !ps) {
        px = (const float*)d_in[0]; pw = (const float*)d_in[1];
        pb = (const float*)d_in[2]; ps = (const int*)d_in[3];
    }

    unsigned short* w2 = (unsigned short*)d_ws;                   // 64 KB
    unsigned short* zf = w2 + N_WIN * OUT_DIM * IN_DIM;           // 388 KB timeline
    float* out = (float*)d_out;

    const int zf_u4 = BB * ZR * IN_DIM / 8;                       // 24832 uint4
    k_zero<<<(zf_u4 + 255) / 256, 256, 0, stream>>>((uint4*)zf, zf_u4);
    k_prep<<<80, 256, 0, stream>>>(px, pw, ps, w2, zf);
    k_gemm<<<dim3(N_REAL / 32, BB), 128, 0, stream>>>(w2, zf, pb, out);
}